// Round 1
// baseline (6042.624 us; speedup 1.0000x reference)
//
#include <hip/hip_runtime.h>
#include <math.h>

#define BB 64
#define TT 128
#define II 4096
#define HH 1024
#define NG 4096   // 4*H
#define K0 2048   // [ha | ca]
#define K1 3072   // [ha | hb | cb]

typedef __attribute__((ext_vector_type(8))) short short8;
typedef __attribute__((ext_vector_type(4))) float f32x4;
typedef __attribute__((ext_vector_type(4))) unsigned short ushort4v;
typedef __attribute__((ext_vector_type(8))) unsigned short ushort8v;

__device__ __forceinline__ unsigned short f2bf(float f){
  union { float f; unsigned u; } v; v.f = f;
  unsigned r = v.u + 0x7fffu + ((v.u >> 16) & 1u);   // RNE
  return (unsigned short)(r >> 16);
}
__device__ __forceinline__ float bf2f(unsigned short u){
  union { float f; unsigned u; } v; v.u = ((unsigned)u) << 16;
  return v.f;
}
__device__ __forceinline__ float sigm(float x){ return 1.f/(1.f + expf(-x)); }

// ---------------- conversion / layout kernels ----------------

__global__ void conv_x(const float* __restrict__ in, unsigned short* __restrict__ outb){
  const size_t i = ((size_t)blockIdx.x*256 + threadIdx.x)*4;
  f32x4 v = *(const f32x4*)(&in[i]);
  ushort4v o; o[0]=f2bf(v[0]); o[1]=f2bf(v[1]); o[2]=f2bf(v[2]); o[3]=f2bf(v[3]);
  *(ushort4v*)(&outb[i]) = o;
}

// Wx0 (4,H,I) -> Wil[n'=4h+g][i], bf16
__global__ void build_Wx0il(const float* __restrict__ Wx0, unsigned short* __restrict__ Wil){
  const int row = blockIdx.y;
  const int c4 = (blockIdx.x*256 + threadIdx.x)*4;
  const int g = row & 3, h = row >> 2;
  f32x4 v = *(const f32x4*)(&Wx0[((size_t)(g*HH + h))*II + c4]);
  ushort4v o; o[0]=f2bf(v[0]); o[1]=f2bf(v[1]); o[2]=f2bf(v[2]); o[3]=f2bf(v[3]);
  *(ushort4v*)(&Wil[(size_t)row*II + c4]) = o;
}

// W0cat[n'=4k+g][0:1024]=Uh0[g][k][:], [1024:2048]=Vc0[j][k][:] (0 for g==2)
__global__ void build_W0cat(const float* __restrict__ Uh0, const float* __restrict__ Vc0,
                            unsigned short* __restrict__ Wc){
  const int row = blockIdx.y;
  const int c4 = (blockIdx.x*256 + threadIdx.x)*4;
  const int g = row & 3, k = row >> 2;
  f32x4 v;
  if (c4 < HH)      v = *(const f32x4*)(&Uh0[((size_t)(g*HH + k))*HH + c4]);
  else if (g == 2)  v = f32x4{0.f,0.f,0.f,0.f};
  else { const int jj = (g==3)?2:g;
         v = *(const f32x4*)(&Vc0[((size_t)(jj*HH + k))*HH + (c4 - HH)]); }
  ushort4v o; o[0]=f2bf(v[0]); o[1]=f2bf(v[1]); o[2]=f2bf(v[2]); o[3]=f2bf(v[3]);
  *(ushort4v*)(&Wc[(size_t)row*K0 + c4]) = o;
}

// W1cat[n'=4k+g][0:1024]=Wx1, [1024:2048]=Uh1, [2048:3072]=Vc1/0
__global__ void build_W1cat(const float* __restrict__ Wx1, const float* __restrict__ Uh1,
                            const float* __restrict__ Vc1, unsigned short* __restrict__ Wc){
  const int row = blockIdx.y;
  const int c4 = (blockIdx.x*256 + threadIdx.x)*4;
  const int g = row & 3, k = row >> 2;
  f32x4 v;
  if (c4 < HH)        v = *(const f32x4*)(&Wx1[((size_t)(g*HH + k))*HH + c4]);
  else if (c4 < 2*HH) v = *(const f32x4*)(&Uh1[((size_t)(g*HH + k))*HH + (c4 - HH)]);
  else if (g == 2)    v = f32x4{0.f,0.f,0.f,0.f};
  else { const int jj = (g==3)?2:g;
         v = *(const f32x4*)(&Vc1[((size_t)(jj*HH + k))*HH + (c4 - 2*HH)]); }
  ushort4v o; o[0]=f2bf(v[0]); o[1]=f2bf(v[1]); o[2]=f2bf(v[2]); o[3]=f2bf(v[3]);
  *(ushort4v*)(&Wc[(size_t)row*K1 + c4]) = o;
}

__global__ void init_state(const float* __restrict__ h0, const float* __restrict__ c0,
  float* ha_f, float* ca_f, float* hb_f, float* cb_f,
  unsigned short* A0w, unsigned short* A1w){
  const int idx = blockIdx.x*256 + threadIdx.x;   // < 65536
  const int b = idx >> 10, k = idx & 1023;
  const float ha = h0[idx], ca = c0[idx];
  const float hb = h0[BB*HH + idx], cb = c0[BB*HH + idx];
  ha_f[idx]=ha; ca_f[idx]=ca; hb_f[idx]=hb; cb_f[idx]=cb;
  A0w[b*K0 + k]          = f2bf(ha);
  A0w[b*K0 + HH + k]     = f2bf(ca);
  A1w[b*K1 + HH + k]     = f2bf(hb);
  A1w[b*K1 + 2*HH + k]   = f2bf(cb);
}

__global__ void finalize(const float* ha_f, const float* hb_f, const float* ca_f, const float* cb_f,
                         float* __restrict__ outp){
  const int idx = blockIdx.x*256 + threadIdx.x;   // < 65536
  outp[idx]            = ha_f[idx];
  outp[BB*HH + idx]    = hb_f[idx];
  outp[2*BB*HH + idx]  = ca_f[idx];
  outp[3*BB*HH + idx]  = cb_f[idx];
}

// ---------------- big precompute GEMM: XZ0 = x . Wx0il^T + b0 ----------------
// A: x_bf [8192][4096] row-major, W: Wx0il [4096][4096] rows = output cols (B^T form)
__global__ __launch_bounds__(256) void gemm_xz0(
  const unsigned short* __restrict__ A, const unsigned short* __restrict__ Wt,
  const float* __restrict__ b0, unsigned short* __restrict__ C)
{
  __shared__ __align__(16) unsigned short Asm[128*72];
  __shared__ __align__(16) unsigned short Wsm[128*72];
  const int tid = threadIdx.x, lane = tid & 63, w = tid >> 6;
  const int wr = w >> 1, wc = w & 1;
  const int m0 = blockIdx.y * 128, n0 = blockIdx.x * 128;
  const int rA = tid >> 3, c8 = (tid & 7) * 8;

  f32x4 acc[4][4];
  #pragma unroll
  for (int i=0;i<4;i++)
    #pragma unroll
    for (int j=0;j<4;j++) acc[i][j] = f32x4{0.f,0.f,0.f,0.f};

  ushort8v pa[4], pw[4];
  #pragma unroll
  for (int s=0;s<4;s++){
    pa[s] = *(const ushort8v*)(&A [(size_t)(m0 + rA + 32*s)*II + c8]);
    pw[s] = *(const ushort8v*)(&Wt[(size_t)(n0 + rA + 32*s)*II + c8]);
  }
  for (int kt = 0; kt < II; kt += 64) {
    __syncthreads();
    #pragma unroll
    for (int s=0;s<4;s++){
      *(ushort8v*)(&Asm[(rA+32*s)*72 + c8]) = pa[s];
      *(ushort8v*)(&Wsm[(rA+32*s)*72 + c8]) = pw[s];
    }
    __syncthreads();
    if (kt + 64 < II){
      #pragma unroll
      for (int s=0;s<4;s++){
        pa[s] = *(const ushort8v*)(&A [(size_t)(m0 + rA + 32*s)*II + kt + 64 + c8]);
        pw[s] = *(const ushort8v*)(&Wt[(size_t)(n0 + rA + 32*s)*II + kt + 64 + c8]);
      }
    }
    #pragma unroll
    for (int ks=0; ks<2; ks++){
      const int kk = ks*32 + (lane>>4)*8;
      short8 af[4], bfv[4];
      #pragma unroll
      for (int rt=0; rt<4; rt++)
        af[rt] = *(const short8*)(&Asm[(wr*64 + rt*16 + (lane&15))*72 + kk]);
      #pragma unroll
      for (int ct=0; ct<4; ct++)
        bfv[ct] = *(const short8*)(&Wsm[(wc*64 + ct*16 + (lane&15))*72 + kk]);
      #pragma unroll
      for (int rt=0; rt<4; rt++)
        #pragma unroll
        for (int ct=0; ct<4; ct++)
          acc[rt][ct] = __builtin_amdgcn_mfma_f32_16x16x32_bf16(af[rt], bfv[ct], acc[rt][ct], 0,0,0);
    }
  }
  #pragma unroll
  for (int rt=0; rt<4; rt++){
    #pragma unroll
    for (int ct=0; ct<4; ct++){
      const int n = n0 + wc*64 + ct*16 + (lane&15);
      const float bias = b0[(n&3)*HH + (n>>2)];
      #pragma unroll
      for (int r=0;r<4;r++){
        const int m = m0 + wr*64 + rt*16 + (lane>>4)*4 + r;
        C[(size_t)m*NG + n] = f2bf(acc[rt][ct][r] + bias);
      }
    }
  }
}

// ---------------- per-step fused kernels ----------------
// phase A: pre = [ha|ca] . W0cat^T  (+XZ0[t], bias already in XZ0) -> gates -> ha,ca
__global__ __launch_bounds__(256) void step_phaseA(
  const unsigned short* __restrict__ A0r, unsigned short* __restrict__ A0w,
  unsigned short* __restrict__ A1w, const unsigned short* __restrict__ W,
  const unsigned short* __restrict__ XZ0,
  float* __restrict__ ca_f, float* __restrict__ ha_f, int t)
{
  __shared__ __align__(16) unsigned short Asm[64*72];
  __shared__ __align__(16) unsigned short Wsm[32*72];
  __shared__ float preSm[64*33];
  const int tid = threadIdx.x, lane = tid & 63, w = tid >> 6;
  const int wc = w & 1, r2 = w >> 1;
  const int n0 = blockIdx.x * 32;
  const int rA = tid >> 3, c8 = (tid & 7) * 8;

  f32x4 acc[2]; acc[0] = f32x4{0.f,0.f,0.f,0.f}; acc[1] = f32x4{0.f,0.f,0.f,0.f};

  ushort8v pa0 = *(const ushort8v*)(&A0r[(size_t)rA*K0 + c8]);
  ushort8v pa1 = *(const ushort8v*)(&A0r[(size_t)(rA+32)*K0 + c8]);
  ushort8v pw  = *(const ushort8v*)(&W  [(size_t)(n0+rA)*K0 + c8]);

  for (int kt = 0; kt < K0; kt += 64) {
    __syncthreads();
    *(ushort8v*)(&Asm[rA*72 + c8])      = pa0;
    *(ushort8v*)(&Asm[(rA+32)*72 + c8]) = pa1;
    *(ushort8v*)(&Wsm[rA*72 + c8])      = pw;
    __syncthreads();
    if (kt + 64 < K0){
      pa0 = *(const ushort8v*)(&A0r[(size_t)rA*K0 + kt + 64 + c8]);
      pa1 = *(const ushort8v*)(&A0r[(size_t)(rA+32)*K0 + kt + 64 + c8]);
      pw  = *(const ushort8v*)(&W  [(size_t)(n0+rA)*K0 + kt + 64 + c8]);
    }
    #pragma unroll
    for (int ks=0; ks<2; ks++){
      const int kk = ks*32 + (lane>>4)*8;
      short8 bv = *(const short8*)(&Wsm[(wc*16 + (lane&15))*72 + kk]);
      #pragma unroll
      for (int rt=0; rt<2; rt++){
        short8 av = *(const short8*)(&Asm[((r2*2+rt)*16 + (lane&15))*72 + kk]);
        acc[rt] = __builtin_amdgcn_mfma_f32_16x16x32_bf16(av, bv, acc[rt], 0,0,0);
      }
    }
  }
  #pragma unroll
  for (int rt=0; rt<2; rt++)
    #pragma unroll
    for (int r=0;r<4;r++)
      preSm[((r2*2+rt)*16 + (lane>>4)*4 + r)*33 + wc*16 + (lane&15)] = acc[rt][r];
  __syncthreads();
  #pragma unroll
  for (int e=0;e<2;e++){
    const int idx = tid + e*256;
    const int b = idx >> 3, kkl = idx & 7;
    float p0 = preSm[b*33 + kkl*4 + 0];
    float p1 = preSm[b*33 + kkl*4 + 1];
    float p2 = preSm[b*33 + kkl*4 + 2];
    float p3 = preSm[b*33 + kkl*4 + 3];
    ushort4v xz = *(const ushort4v*)(&XZ0[((size_t)(b*TT + t))*NG + n0 + kkl*4]);
    p0 += bf2f(xz[0]); p1 += bf2f(xz[1]); p2 += bf2f(xz[2]); p3 += bf2f(xz[3]);
    const float ig = sigm(p0), fg = sigm(p1), gg = tanhf(p2), og = sigm(p3);
    const int kk = blockIdx.x*8 + kkl;
    const int si = b*HH + kk;
    const float cn = fg*ca_f[si] + ig*gg;
    const float hn = og*tanhf(cn);
    ca_f[si] = cn; ha_f[si] = hn;
    const unsigned short h16 = f2bf(hn), c16 = f2bf(cn);
    A0w[b*K0 + kk]      = h16;
    A0w[b*K0 + HH + kk] = c16;
    A1w[b*K1 + kk]      = h16;
  }
}

// phase B: pre = [ha|hb|cb] . W1cat^T + b1 -> gates -> hb,cb, out[t]
__global__ __launch_bounds__(256) void step_phaseB(
  const unsigned short* __restrict__ A1r, unsigned short* __restrict__ A1w,
  const unsigned short* __restrict__ W, const float* __restrict__ b1,
  float* __restrict__ cb_f, float* __restrict__ hb_f,
  float* __restrict__ out, int t)
{
  __shared__ __align__(16) unsigned short Asm[64*72];
  __shared__ __align__(16) unsigned short Wsm[32*72];
  __shared__ float preSm[64*33];
  const int tid = threadIdx.x, lane = tid & 63, w = tid >> 6;
  const int wc = w & 1, r2 = w >> 1;
  const int n0 = blockIdx.x * 32;
  const int rA = tid >> 3, c8 = (tid & 7) * 8;

  f32x4 acc[2]; acc[0] = f32x4{0.f,0.f,0.f,0.f}; acc[1] = f32x4{0.f,0.f,0.f,0.f};

  ushort8v pa0 = *(const ushort8v*)(&A1r[(size_t)rA*K1 + c8]);
  ushort8v pa1 = *(const ushort8v*)(&A1r[(size_t)(rA+32)*K1 + c8]);
  ushort8v pw  = *(const ushort8v*)(&W  [(size_t)(n0+rA)*K1 + c8]);

  for (int kt = 0; kt < K1; kt += 64) {
    __syncthreads();
    *(ushort8v*)(&Asm[rA*72 + c8])      = pa0;
    *(ushort8v*)(&Asm[(rA+32)*72 + c8]) = pa1;
    *(ushort8v*)(&Wsm[rA*72 + c8])      = pw;
    __syncthreads();
    if (kt + 64 < K1){
      pa0 = *(const ushort8v*)(&A1r[(size_t)rA*K1 + kt + 64 + c8]);
      pa1 = *(const ushort8v*)(&A1r[(size_t)(rA+32)*K1 + kt + 64 + c8]);
      pw  = *(const ushort8v*)(&W  [(size_t)(n0+rA)*K1 + kt + 64 + c8]);
    }
    #pragma unroll
    for (int ks=0; ks<2; ks++){
      const int kk = ks*32 + (lane>>4)*8;
      short8 bv = *(const short8*)(&Wsm[(wc*16 + (lane&15))*72 + kk]);
      #pragma unroll
      for (int rt=0; rt<2; rt++){
        short8 av = *(const short8*)(&Asm[((r2*2+rt)*16 + (lane&15))*72 + kk]);
        acc[rt] = __builtin_amdgcn_mfma_f32_16x16x32_bf16(av, bv, acc[rt], 0,0,0);
      }
    }
  }
  #pragma unroll
  for (int rt=0; rt<2; rt++)
    #pragma unroll
    for (int r=0;r<4;r++)
      preSm[((r2*2+rt)*16 + (lane>>4)*4 + r)*33 + wc*16 + (lane&15)] = acc[rt][r];
  __syncthreads();
  #pragma unroll
  for (int e=0;e<2;e++){
    const int idx = tid + e*256;
    const int b = idx >> 3, kkl = idx & 7;
    const int kk = blockIdx.x*8 + kkl;
    float p0 = preSm[b*33 + kkl*4 + 0] + b1[kk];
    float p1 = preSm[b*33 + kkl*4 + 1] + b1[HH + kk];
    float p2 = preSm[b*33 + kkl*4 + 2] + b1[2*HH + kk];
    float p3 = preSm[b*33 + kkl*4 + 3] + b1[3*HH + kk];
    const float ig = sigm(p0), fg = sigm(p1), gg = tanhf(p2), og = sigm(p3);
    const int si = b*HH + kk;
    const float cn = fg*cb_f[si] + ig*gg;
    const float hn = og*tanhf(cn);
    cb_f[si] = cn; hb_f[si] = hn;
    A1w[b*K1 + HH + kk]   = f2bf(hn);
    A1w[b*K1 + 2*HH + kk] = f2bf(cn);
    out[((size_t)b*TT + t)*HH + kk] = hn;
  }
}

// ---------------- host ----------------

extern "C" void kernel_launch(void* const* d_in, const int* in_sizes, int n_in,
                              void* d_out, int out_size, void* d_ws, size_t ws_size,
                              hipStream_t stream)
{
  (void)in_sizes; (void)n_in; (void)out_size; (void)ws_size;
  const float* x   = (const float*)d_in[0];
  const float* h0  = (const float*)d_in[1];
  const float* c0  = (const float*)d_in[2];
  const float* Wx0 = (const float*)d_in[3];
  const float* Uh0 = (const float*)d_in[4];
  const float* Vc0 = (const float*)d_in[5];
  const float* b0  = (const float*)d_in[6];
  const float* Wx1 = (const float*)d_in[7];
  const float* Uh1 = (const float*)d_in[8];
  const float* Vc1 = (const float*)d_in[9];
  const float* b1  = (const float*)d_in[10];
  float* out = (float*)d_out;

  char* ws = (char*)d_ws;
  size_t off = 0;
  auto alloc = [&](size_t bytes) { char* p = ws + off; off += (bytes + 255) & ~(size_t)255; return p; };
  unsigned short* x_bf  = (unsigned short*)alloc((size_t)BB*TT*II*2);
  unsigned short* Wx0il = (unsigned short*)alloc((size_t)NG*II*2);
  unsigned short* XZ0   = (unsigned short*)alloc((size_t)BB*TT*NG*2);
  unsigned short* W0cat = (unsigned short*)alloc((size_t)NG*K0*2);
  unsigned short* W1cat = (unsigned short*)alloc((size_t)NG*K1*2);
  unsigned short* A0b[2] = { (unsigned short*)alloc((size_t)BB*K0*2), (unsigned short*)alloc((size_t)BB*K0*2) };
  unsigned short* A1b[2] = { (unsigned short*)alloc((size_t)BB*K1*2), (unsigned short*)alloc((size_t)BB*K1*2) };
  float* ha_f = (float*)alloc((size_t)BB*HH*4);
  float* ca_f = (float*)alloc((size_t)BB*HH*4);
  float* hb_f = (float*)alloc((size_t)BB*HH*4);
  float* cb_f = (float*)alloc((size_t)BB*HH*4);

  conv_x<<<32768, 256, 0, stream>>>(x, x_bf);
  build_Wx0il<<<dim3(4,4096), 256, 0, stream>>>(Wx0, Wx0il);
  build_W0cat<<<dim3(2,4096), 256, 0, stream>>>(Uh0, Vc0, W0cat);
  build_W1cat<<<dim3(3,4096), 256, 0, stream>>>(Wx1, Uh1, Vc1, W1cat);
  init_state<<<256, 256, 0, stream>>>(h0, c0, ha_f, ca_f, hb_f, cb_f, A0b[0], A1b[0]);
  gemm_xz0<<<dim3(32,64), 256, 0, stream>>>(x_bf, Wx0il, b0, XZ0);

  for (int t = 0; t < TT; t++) {
    const int q = t & 1;
    step_phaseA<<<128, 256, 0, stream>>>(A0b[q], A0b[q^1], A1b[q], W0cat, XZ0, ca_f, ha_f, t);
    step_phaseB<<<128, 256, 0, stream>>>(A1b[q], A1b[q^1], W1cat, b1, cb_f, hb_f, out, t);
  }
  finalize<<<256, 256, 0, stream>>>(ha_f, hb_f, ca_f, cb_f, out + (size_t)BB*TT*HH);
}